// Round 1
// baseline (1019.445 us; speedup 1.0000x reference)
//
#include <hip/hip_runtime.h>
#include <math.h>

// ---------------- FDTD time-skewed LDS tiling ----------------
// 400x400 grid, 300 steps, batch 2. Tile: 40x40 interior + halo 12 -> 64x64
// extended region in LDS (+1 ghost ring => pitch 66). Each round kernel
// advances 12 steps locally; validity cone [s, 63-s] covers interior [12,51]
// exactly after 12 steps. 25 rounds x 12 = 300 steps.
#define NXg 400
#define NYg 400
#define NN (NXg * NYg)
#define SRC_I 30
#define DET_I 370
#define TILE_B 40
#define HALO 12
#define EXT 64          // TILE_B + 2*HALO
#define PITCH 66        // EXT + 2 ghost
#define NTI 10          // tiles per dim (10*40 = 400 exact)
#define ROUNDS 25
#define RSTEPS 12
#define NB 2

static constexpr float DT_F     = (float)(0.5 * 25e-9 / 299792458.0);     // COURANT*DX/C0
static constexpr float PERIOD_F = (float)(1550e-9 / 299792458.0);         // WAVELENGTH/C0
static constexpr float TWOPI_F  = (float)(2.0 * 3.14159265358979323846);
static constexpr float PI_F     = (float)3.14159265358979323846;

// ---- one-time (per call) setup: zero states, build rc = COURANT/eps, damp profile ----
__global__ void fdtd_setup(const float* __restrict__ radius,
                           float* __restrict__ Ez_g, float* __restrict__ Hx_g,
                           float* __restrict__ Hy_g, float* __restrict__ rc_g,
                           float* __restrict__ px_g)
{
    int idx = blockIdx.x * blockDim.x + threadIdx.x;
    if (idx >= NN) return;
    int i = idx / NYg, j = idx % NYg;

    // zero state for both batches (d_ws is poisoned 0xAA before every call)
    Ez_g[idx] = 0.f; Ez_g[idx + NN] = 0.f;
    Hx_g[idx] = 0.f; Hx_g[idx + NN] = 0.f;
    Hy_g[idx] = 0.f; Hy_g[idx + NN] = 0.f;

    float eps = 1.0f;
    int dj = j - 70;  // port columns: [70..89],[150..169],[230..249],[310..329]
    bool port = (dj >= 0) && (dj < 260) && ((dj % 80) < 20);
    if (port && (i < SRC_I || i >= DET_I)) eps = 2.8f;
    if (i >= 80 && i < 320 && j >= 80 && j < 320) {
        // design region: 8x8 circles, spacing 30, centers 15+30k; r<0.3 -> 0
        // (note: r=0 still captures its exact center pixel, dist2<=0)
        float x = (float)(i - 80), y = (float)(j - 80);
        bool inside = false;
        for (int a = 0; a < 64; ++a) {
            float r = radius[a];
            r = (r < 0.3f) ? 0.f : r;
            float cx = (float)(15 + 30 * (a >> 3));
            float cy = (float)(15 + 30 * (a & 7));
            float dx = x - cx, dy = y - cy;
            if (dx * dx + dy * dy <= r * r) inside = true;
        }
        eps = inside ? 1.0f : 2.8f;
    }
    rc_g[idx] = 0.5f / eps;

    if (idx < NXg) {
        // damp profile in double, then cast: matches numpy f64 exp -> f32
        double prof = 1.0;
        if (idx < 10) {
            double rmp = (10.0 - (double)idx - 0.5) / 10.0;
            prof = exp(-0.5 * rmp * rmp * rmp);
        } else if (idx >= NXg - 10) {
            double rmp = ((double)(idx - (NXg - 10)) + 0.5) / 10.0;
            prof = exp(-0.5 * rmp * rmp * rmp);
        }
        px_g[idx] = (float)prof;
    }
}

// ---- one round: load ext tile -> 12 local steps in LDS -> store interior ----
__global__ __launch_bounds__(512)
void fdtd_round(const float* __restrict__ phase,
                float* __restrict__ Ez_g, float* __restrict__ Hx_g,
                float* __restrict__ Hy_g, const float* __restrict__ rc_g,
                const float* __restrict__ px_g, int t0)
{
    __shared__ float sEz[PITCH * PITCH];
    __shared__ float sHx[PITCH * PITCH];
    __shared__ float sHy[PITCH * PITCH];
    __shared__ float sPx[PITCH];
    __shared__ float sPy[PITCH];

    const int tid = threadIdx.x;
    const int b   = blockIdx.z;
    const int gx0 = blockIdx.x * TILE_B - HALO;   // global i of ext cell li=0
    const int gy0 = blockIdx.y * TILE_B - HALO;
    const int lj  = tid & 63;                     // lane -> column within ext tile
    const int r0  = tid >> 6;                     // 0..7 row group
    const int gj  = gy0 + lj;
    const size_t bb = (size_t)b * NN;

    // damp profile slices + zero the ghost ring (never written afterwards)
    for (int k = tid; k < PITCH; k += 512) {
        int gii = gx0 + k - 1;
        int gjj = gy0 + k - 1;
        sPx[k] = (gii >= 0 && gii < NXg) ? px_g[gii] : 0.f;
        sPy[k] = (gjj >= 0 && gjj < NYg) ? px_g[gjj] : 0.f;
        sEz[k] = 0.f; sHx[k] = 0.f; sHy[k] = 0.f;                     // top
        int bot = (PITCH - 1) * PITCH + k;
        sEz[bot] = 0.f; sHx[bot] = 0.f; sHy[bot] = 0.f;               // bottom
        int lef = k * PITCH;
        sEz[lef] = 0.f; sHx[lef] = 0.f; sHy[lef] = 0.f;               // left
        int rig = lef + PITCH - 1;
        sEz[rig] = 0.f; sHx[rig] = 0.f; sHy[rig] = 0.f;               // right
    }

    // load ext tile (out-of-grid cells -> 0; they stay 0: damp=0, no source there)
    float rcv[8];
    const bool jin = (gj >= 0) && (gj < NYg);
    #pragma unroll
    for (int k = 0; k < 8; ++k) {
        const int li = r0 + 8 * k;
        const int gi = gx0 + li;
        const int c  = (li + 1) * PITCH + (lj + 1);
        const bool in = jin && (gi >= 0) && (gi < NXg);
        float ez = 0.f, hx = 0.f, hy = 0.f, rc = 1.f;
        if (in) {
            const size_t go = bb + (size_t)gi * NYg + gj;
            ez = Ez_g[go]; hx = Hx_g[go]; hy = Hy_g[go];
            rc = rc_g[(size_t)gi * NYg + gj];
        }
        sEz[c] = ez; sHx[c] = hx; sHy[c] = hy; rcv[k] = rc;
    }
    __syncthreads();

    const float pyv = sPy[lj + 1];
    const int djp = gj - 70;
    const int pport = (djp >= 0 && djp < 260 && (djp % 80) < 20) ? (djp / 80) : -1;
    const float phv = (pport >= 0) ? phase[b * 4 + pport] : 0.f;
    const bool gYlt = (gj < NYg - 1);
    const bool gYgt = (gj > 0);

    for (int s = 0; s < RSTEPS; ++s) {
        // ---- H update: Hx -= C*dEz/dy, Hy += C*dEz/dx, then damp ----
        #pragma unroll
        for (int k = 0; k < 8; ++k) {
            const int li = r0 + 8 * k;
            const int gi = gx0 + li;
            const int c  = (li + 1) * PITCH + (lj + 1);
            const float ez  = sEz[c];
            const float dey = gYlt ? (sEz[c + 1] - ez) : 0.f;            // pad end axis1
            const float dex = (gi < NXg - 1) ? (sEz[c + PITCH] - ez) : 0.f; // pad end axis0
            const float damp = sPx[li + 1] * pyv;
            sHx[c] = damp * (sHx[c] - 0.5f * dey);
            sHy[c] = damp * (sHy[c] + 0.5f * dex);
        }
        __syncthreads();
        const float tf = (float)(t0 + s);
        // ---- E update + soft source ----
        #pragma unroll
        for (int k = 0; k < 8; ++k) {
            const int li = r0 + 8 * k;
            const int gi = gx0 + li;
            const int c  = (li + 1) * PITCH + (lj + 1);
            const float hx = sHx[c];
            const float hy = sHy[c];
            const float dhyx = (gi > 0) ? (hy - sHy[c - PITCH]) : 0.f;   // pad start axis0
            const float dhxy = gYgt ? (hx - sHx[c - 1]) : 0.f;           // pad start axis1
            const float damp = sPx[li + 1] * pyv;
            float ez = damp * (sEz[c] + rcv[k] * (dhyx - dhxy));
            if (gi == SRC_I && pport >= 0) {
                const float a = tf * DT_F;                                // JAX f32 op order
                ez += sinf(TWOPI_F * a / PERIOD_F + PI_F * phv);
            }
            sEz[c] = ez;
        }
        __syncthreads();
    }

    // store interior [HALO, HALO+TILE_B) — exact tiling, no clipping needed
    #pragma unroll
    for (int k = 0; k < 8; ++k) {
        const int li = r0 + 8 * k;
        if (li >= HALO && li < HALO + TILE_B && lj >= HALO && lj < HALO + TILE_B) {
            const int gi = gx0 + li;
            const size_t go = bb + (size_t)gi * NYg + gj;
            const int c = (li + 1) * PITCH + (lj + 1);
            Ez_g[go] = sEz[c];
            Hx_g[go] = sHx[c];
            Hy_g[go] = sHy[c];
        }
    }
}

// ---- detector gather: out[b][p][k] = Ez[DET_I, 80*(p+1)-10+k] ----
__global__ void fdtd_gather(const float* __restrict__ Ez_g, float* __restrict__ out)
{
    int idx = threadIdx.x;
    if (idx < NB * 80) {
        int b = idx / 80, rem = idx % 80, p = rem / 20, k = rem % 20;
        int gj = (p + 1) * 80 - 10 + k;
        out[idx] = Ez_g[(size_t)b * NN + (size_t)DET_I * NYg + gj];
    }
}

extern "C" void kernel_launch(void* const* d_in, const int* in_sizes, int n_in,
                              void* d_out, int out_size, void* d_ws, size_t ws_size,
                              hipStream_t stream)
{
    const float* phase  = (const float*)d_in[0];   // (2,4) f32
    const float* radius = (const float*)d_in[1];   // (8,8) f32
    float* ws = (float*)d_ws;
    // workspace layout (floats): Ez[2*NN] | Hx[2*NN] | Hy[2*NN] | rc[NN] | px[400]
    float* Ez_g = ws;
    float* Hx_g = ws + 2 * NN;
    float* Hy_g = ws + 4 * NN;
    float* rc_g = ws + 6 * NN;
    float* px_g = ws + 7 * NN;

    fdtd_setup<<<(NN + 255) / 256, 256, 0, stream>>>(radius, Ez_g, Hx_g, Hy_g, rc_g, px_g);

    dim3 grid(NTI, NTI, NB);
    for (int r = 0; r < ROUNDS; ++r) {
        fdtd_round<<<grid, 512, 0, stream>>>(phase, Ez_g, Hx_g, Hy_g, rc_g, px_g, r * RSTEPS);
    }

    fdtd_gather<<<1, 256, 0, stream>>>(Ez_g, (float*)d_out);
}

// Round 2
// 542.496 us; speedup vs baseline: 1.8792x; 1.8792x over previous
//
#include <hip/hip_runtime.h>
#include <math.h>

// ---------------- FDTD time-skewed tiling, register-resident fields ----------------
// 400x400 grid, 300 steps, batch 2. Tile: 40x40 interior + halo 12 -> 64x64 ext.
// Block = 512 threads = 8 waves; wave w owns ext rows [8w, 8w+8), lane = ext col.
// Fields live in registers (8 rows/lane). Column neighbors via __shfl; wave-boundary
// rows via tiny ping-pong LDS exchange; ONE barrier per step. 25 rounds x 12 steps.
#define NXg 400
#define NYg 400
#define NN (NXg * NYg)
#define SRC_I 30
#define DET_I 370
#define TILE_B 40
#define HALO 12
#define NTI 10          // tiles per dim (10*40 = 400 exact)
#define ROUNDS 25
#define RSTEPS 12
#define NB 2
#define XSLOT 576       // 9 slots * 64 lanes (slot 0 or 8 = ghost zeros)

static constexpr float DT_F     = (float)(0.5 * 25e-9 / 299792458.0);     // COURANT*DX/C0
static constexpr float PERIOD_F = (float)(1550e-9 / 299792458.0);         // WAVELENGTH/C0
static constexpr float TWOPI_F  = (float)(2.0 * 3.14159265358979323846);
static constexpr float PI_F     = (float)3.14159265358979323846;

// shared helper so the redundant "row above" Hy update compiles identically
__device__ __forceinline__ float hupd(float damp, float h, float d) {
    return damp * (h + 0.5f * d);
}

// ---- one-time (per call) setup: zero states, build rc = COURANT/eps, damp profile ----
__global__ void fdtd_setup(const float* __restrict__ radius,
                           float* __restrict__ Ez_g, float* __restrict__ Hx_g,
                           float* __restrict__ Hy_g, float* __restrict__ rc_g,
                           float* __restrict__ px_g)
{
    int idx = blockIdx.x * blockDim.x + threadIdx.x;
    if (idx >= NN) return;
    int i = idx / NYg, j = idx % NYg;

    Ez_g[idx] = 0.f; Ez_g[idx + NN] = 0.f;
    Hx_g[idx] = 0.f; Hx_g[idx + NN] = 0.f;
    Hy_g[idx] = 0.f; Hy_g[idx + NN] = 0.f;

    float eps = 1.0f;
    int dj = j - 70;  // port columns: [70..89],[150..169],[230..249],[310..329]
    bool port = (dj >= 0) && (dj < 260) && ((dj % 80) < 20);
    if (port && (i < SRC_I || i >= DET_I)) eps = 2.8f;
    if (i >= 80 && i < 320 && j >= 80 && j < 320) {
        float x = (float)(i - 80), y = (float)(j - 80);
        bool inside = false;
        for (int a = 0; a < 64; ++a) {
            float r = radius[a];
            r = (r < 0.3f) ? 0.f : r;
            float cx = (float)(15 + 30 * (a >> 3));
            float cy = (float)(15 + 30 * (a & 7));
            float dx = x - cx, dy = y - cy;
            if (dx * dx + dy * dy <= r * r) inside = true;
        }
        eps = inside ? 1.0f : 2.8f;
    }
    rc_g[idx] = 0.5f / eps;

    if (idx < NXg) {
        double prof = 1.0;
        if (idx < 10) {
            double rmp = (10.0 - (double)idx - 0.5) / 10.0;
            prof = exp(-0.5 * rmp * rmp * rmp);
        } else if (idx >= NXg - 10) {
            double rmp = ((double)(idx - (NXg - 10)) + 0.5) / 10.0;
            prof = exp(-0.5 * rmp * rmp * rmp);
        }
        px_g[idx] = (float)prof;
    }
}

// ---- one round: load regs -> 12 local steps (regs + shuffles) -> store interior ----
__global__ __launch_bounds__(512)
void fdtd_round(const float* __restrict__ phase,
                float* __restrict__ Ez_g, float* __restrict__ Hx_g,
                float* __restrict__ Hy_g, const float* __restrict__ rc_g,
                const float* __restrict__ px_g, int t0)
{
    // ping-pong wave-boundary exchange buffers
    __shared__ float xEz0[2][XSLOT];   // slot w   = wave w's Ez row0; slot 8 ghost
    __shared__ float xEz7[2][XSLOT];   // slot w+1 = wave w's Ez row7; slot 0 ghost
    __shared__ float xHy7[2][XSLOT];   // slot w+1 = wave w's Hy row7 (pre-update)

    const int tid = threadIdx.x;
    const int w   = tid >> 6;
    const int lj  = tid & 63;
    const int b   = blockIdx.z;
    const int gx0 = blockIdx.x * TILE_B - HALO;
    const int gy0 = blockIdx.y * TILE_B - HALO;
    const int gj  = gy0 + lj;
    const int gib = gx0 + 8 * w;       // global row of register r=0
    const size_t bb = (size_t)b * NN;

    if (tid < 64) {
        #pragma unroll
        for (int p = 0; p < 2; ++p) {
            xEz0[p][512 + tid] = 0.f;
            xEz7[p][tid] = 0.f;
            xHy7[p][tid] = 0.f;
        }
    }

    const bool jin = (gj >= 0) && (gj < NYg);
    const float pyv = jin ? px_g[gj] : 0.f;

    float Ez[8], Hx[8], Hy[8], rc[8], dmp[8];
    #pragma unroll
    for (int r = 0; r < 8; ++r) {
        const int gi = gib + r;
        const bool in = jin && (gi >= 0) && (gi < NXg);
        if (in) {
            const size_t go = bb + (size_t)gi * NYg + gj;
            Ez[r] = Ez_g[go]; Hx[r] = Hx_g[go]; Hy[r] = Hy_g[go];
            rc[r] = rc_g[(size_t)gi * NYg + gj];
            dmp[r] = px_g[gi] * pyv;
        } else {
            Ez[r] = 0.f; Hx[r] = 0.f; Hy[r] = 0.f; rc[r] = 0.5f; dmp[r] = 0.f;
        }
    }
    float dmpA = 0.f;   // damp of the row just above this wave's rows
    { const int giA = gib - 1; if (jin && giA >= 0 && giA < NXg) dmpA = px_g[giA] * pyv; }

    const int djp = gj - 70;
    const int pport = (djp >= 0 && djp < 260 && (djp % 80) < 20) ? (djp / 80) : -1;
    const float phv = (pport >= 0) ? phase[b * 4 + pport] : 0.f;
    const bool gYlt = (gj < NYg - 1);
    const bool gYgt = (gj > 0);
    const bool hasSrc = (gib <= SRC_I) && (SRC_I < gib + 8);

    for (int s = 0; s < RSTEPS; ++s) {
        const int p = s & 1;
        // publish wave-boundary rows (pre-update values)
        xEz0[p][(w << 6) + lj] = Ez[0];
        xEz7[p][((w + 1) << 6) + lj] = Ez[7];
        xHy7[p][((w + 1) << 6) + lj] = Hy[7];
        __syncthreads();
        const float ezB  = xEz0[p][((w + 1) << 6) + lj];   // Ez of row below (wave w+1 row0)
        const float ezA7 = xEz7[p][(w << 6) + lj];         // Ez of row above (wave w-1 row7)
        const float hyA7 = xHy7[p][(w << 6) + lj];         // Hy of row above (pre-update)
        // redundant Hy update of the row above — bitwise-identical inputs/expression
        const float dexA = (gib - 1 < NXg - 1) ? (Ez[0] - ezA7) : 0.f;
        const float hyA  = hupd(dmpA, hyA7, dexA);

        // ---- H update (registers + shuffles) ----
        float ezn[8];
        #pragma unroll
        for (int r = 0; r < 7; ++r) ezn[r] = Ez[r + 1];
        ezn[7] = ezB;
        #pragma unroll
        for (int r = 0; r < 8; ++r) {
            const int gi = gib + r;
            const float ezr = __shfl_down(Ez[r], 1, 64);
            const float dey = gYlt ? (ezr - Ez[r]) : 0.f;
            const float dex = (gi < NXg - 1) ? (ezn[r] - Ez[r]) : 0.f;
            Hx[r] = hupd(dmp[r], Hx[r], -dey);
            Hy[r] = hupd(dmp[r], Hy[r], dex);
        }

        // ---- E update + soft source ----
        const float tf = (float)(t0 + s);
        float hyprev = hyA;
        #pragma unroll
        for (int r = 0; r < 8; ++r) {
            const int gi = gib + r;
            const float hxl = __shfl_up(Hx[r], 1, 64);
            const float dhyx = (gi > 0) ? (Hy[r] - hyprev) : 0.f;
            const float dhxy = gYgt ? (Hx[r] - hxl) : 0.f;
            float ez = dmp[r] * (Ez[r] + rc[r] * (dhyx - dhxy));
            if (hasSrc && (gi == SRC_I) && (pport >= 0)) {
                const float a = tf * DT_F;                  // JAX f32 op order
                ez += sinf(TWOPI_F * a / PERIOD_F + PI_F * phv);
            }
            Ez[r] = ez;
            hyprev = Hy[r];
        }
        // single barrier per step: ping-pong buffers make a 2nd barrier unnecessary
    }

    // store interior [HALO, HALO+TILE_B) — exact tiling
    if (lj >= HALO && lj < HALO + TILE_B) {
        #pragma unroll
        for (int r = 0; r < 8; ++r) {
            const int li = (w << 3) + r;
            if (li >= HALO && li < HALO + TILE_B) {
                const int gi = gx0 + li;
                const size_t go = bb + (size_t)gi * NYg + gj;
                Ez_g[go] = Ez[r];
                Hx_g[go] = Hx[r];
                Hy_g[go] = Hy[r];
            }
        }
    }
}

// ---- detector gather: out[b][p][k] = Ez[DET_I, 80*(p+1)-10+k] ----
__global__ void fdtd_gather(const float* __restrict__ Ez_g, float* __restrict__ out)
{
    int idx = threadIdx.x;
    if (idx < NB * 80) {
        int b = idx / 80, rem = idx % 80, p = rem / 20, k = rem % 20;
        int gj = (p + 1) * 80 - 10 + k;
        out[idx] = Ez_g[(size_t)b * NN + (size_t)DET_I * NYg + gj];
    }
}

extern "C" void kernel_launch(void* const* d_in, const int* in_sizes, int n_in,
                              void* d_out, int out_size, void* d_ws, size_t ws_size,
                              hipStream_t stream)
{
    const float* phase  = (const float*)d_in[0];   // (2,4) f32
    const float* radius = (const float*)d_in[1];   // (8,8) f32
    float* ws = (float*)d_ws;
    // workspace layout (floats): Ez[2*NN] | Hx[2*NN] | Hy[2*NN] | rc[NN] | px[400]
    float* Ez_g = ws;
    float* Hx_g = ws + 2 * NN;
    float* Hy_g = ws + 4 * NN;
    float* rc_g = ws + 6 * NN;
    float* px_g = ws + 7 * NN;

    fdtd_setup<<<(NN + 255) / 256, 256, 0, stream>>>(radius, Ez_g, Hx_g, Hy_g, rc_g, px_g);

    dim3 grid(NTI, NTI, NB);
    for (int r = 0; r < ROUNDS; ++r) {
        fdtd_round<<<grid, 512, 0, stream>>>(phase, Ez_g, Hx_g, Hy_g, rc_g, px_g, r * RSTEPS);
    }

    fdtd_gather<<<1, 256, 0, stream>>>(Ez_g, (float*)d_out);
}